// Round 3
// baseline (61411.615 us; speedup 1.0000x reference)
//
#include <hip/hip_runtime.h>
#include <hip/hip_cooperative_groups.h>
#include <cmath>

namespace cg = cooperative_groups;

// ---------------------------------------------------------------------------
// GridGRU on MI355X. Round 3: bf16 MFMA GEMMs + persistent cooperative scan.
// N=32, T=512, D=H=1024. weight (2048,6144) row-major f32, bias 6144.
// ---------------------------------------------------------------------------

#define LDW 6144
typedef float  f32x4 __attribute__((ext_vector_type(4)));
typedef short  s16x8 __attribute__((ext_vector_type(8)));

__device__ __forceinline__ float sigf(float v){ return 1.f/(1.f+__expf(-v)); }
__device__ __forceinline__ unsigned short f2b(float f){
    unsigned u = __float_as_uint(f);
    return (unsigned short)((u + 0x7FFFu + ((u>>16)&1u)) >> 16);
}

// ---- WT[j][k] = bf16(weight[k][j]); j<6144, k<2048 -------------------------
__global__ __launch_bounds__(256)
void k_wt(const float* __restrict__ w, unsigned short* __restrict__ wt)
{
    __shared__ float t[64][65];
    const int j0 = blockIdx.x*64, k0 = blockIdx.y*64;
    for (int i = threadIdx.x; i < 4096; i += 256) {
        int r = i>>6, c = i&63;
        t[r][c] = w[(size_t)(k0+r)*LDW + j0 + c];
    }
    __syncthreads();
    for (int i = threadIdx.x; i < 4096; i += 256) {
        int jr = i>>6, kc = i&63;
        wt[(size_t)(j0+jr)*2048 + k0 + kc] = f2b(t[kc][jr]);
    }
}

// ---- WhT[j][k] = weight[1024+k][j] f32; j<3072, k<1024 ---------------------
__global__ __launch_bounds__(256)
void k_wht(const float* __restrict__ w, float* __restrict__ wht)
{
    __shared__ float t[64][65];
    const int j0 = blockIdx.x*64, k0 = blockIdx.y*64;
    for (int i = threadIdx.x; i < 4096; i += 256) {
        int r = i>>6, c = i&63;
        t[r][c] = w[(size_t)(1024+k0+r)*LDW + j0 + c];
    }
    __syncthreads();
    for (int i = threadIdx.x; i < 4096; i += 256) {
        int jr = i>>6, kc = i&63;
        wht[(size_t)(j0+jr)*1024 + k0 + kc] = t[kc][jr];
    }
}

// ---- x (f32) -> bf16 -------------------------------------------------------
__global__ __launch_bounds__(256)
void k_xbf(const float* __restrict__ x, unsigned short* __restrict__ o)
{
    long i = ((long)blockIdx.x*256 + threadIdx.x)*4;
    float4 v = *(const float4*)&x[i];
    ushort4 r = { f2b(v.x), f2b(v.y), f2b(v.z), f2b(v.w) };
    *(ushort4*)&o[i] = r;
}

// ---------------------------------------------------------------------------
// bf16 MFMA GEMM: C[M,N] = A[M,K] * B[K,N] (+bias, +epilogue).
// BM=BN=128, BK=32, 256 threads (4 waves), wave -> 64x64, acc 4x4 of 16x16.
// A row-major bf16 lda=1024 (concat-K switches buffer at k=1024).
// B supplied TRANSPOSED: Bw[n][k] bf16, ld 2048 (slice of WT).
// AMODE: 0 linear; 1 gates (row -> x[(row>>6)*512 + t0 + (row&63)]); 2 concat.
// EMODE: 0: C[row*ldc+col] = v+bias
//        1: s=sig(v+b); col<1024 -> UD=s ; else RX = bf16(s * X)
//        2: hc=tanh(v+b); C = X + UD*(hc-X)
// ---------------------------------------------------------------------------
template<int AMODE, int EMODE>
__global__ __launch_bounds__(256)
void gemm_mfma(const unsigned short* __restrict__ A1,
               const unsigned short* __restrict__ A2,
               const unsigned short* __restrict__ Bw,
               float* __restrict__ C, int ldc,
               const float* __restrict__ bias,
               const float* __restrict__ X,
               float* __restrict__ UD,
               unsigned short* __restrict__ RX,
               int K, int t0)
{
    __shared__ unsigned short Als[128*32];
    __shared__ unsigned short Bls[128*32];
    const int tid = threadIdx.x;
    const int m_base = blockIdx.y*128;
    const int n_base = blockIdx.x*128;
    const int row0 = tid>>2, row1 = row0+64, quad = tid&3;
    const int wv = tid>>6, lane = tid&63;
    const int wr = (wv>>1)*64, wc = (wv&1)*64;
    const int l15 = lane&15, l4 = lane>>4;

    f32x4 acc[4][4] = {};

    for (int k0 = 0; k0 < K; k0 += 32) {
        const int kq = k0 + quad*8;
        s16x8 a0, a1, b0, b1;
        {
            long r0 = m_base + row0, r1 = m_base + row1;
            const unsigned short *p0, *p1;
            if (AMODE == 1) {
                long g0 = (r0>>6)*512 + t0 + (r0&63);
                long g1 = (r1>>6)*512 + t0 + (r1&63);
                p0 = A1 + g0*1024 + kq; p1 = A1 + g1*1024 + kq;
            } else if (AMODE == 2 && k0 >= 1024) {
                p0 = A2 + r0*1024 + (kq-1024); p1 = A2 + r1*1024 + (kq-1024);
            } else {
                p0 = A1 + r0*1024 + kq; p1 = A1 + r1*1024 + kq;
            }
            a0 = *(const s16x8*)p0; a1 = *(const s16x8*)p1;
        }
        b0 = *(const s16x8*)(Bw + (size_t)(n_base+row0)*2048 + kq);
        b1 = *(const s16x8*)(Bw + (size_t)(n_base+row1)*2048 + kq);
        __syncthreads();                       // prior LDS reads complete
        *(s16x8*)&Als[row0*32 + quad*8] = a0;
        *(s16x8*)&Als[row1*32 + quad*8] = a1;
        *(s16x8*)&Bls[row0*32 + quad*8] = b0;
        *(s16x8*)&Bls[row1*32 + quad*8] = b1;
        __syncthreads();                       // tile ready
        s16x8 af[4], bfr[4];
#pragma unroll
        for (int i = 0; i < 4; ++i) {
            af[i]  = *(const s16x8*)&Als[(wr + i*16 + l15)*32 + l4*8];
            bfr[i] = *(const s16x8*)&Bls[(wc + i*16 + l15)*32 + l4*8];
        }
#pragma unroll
        for (int mi = 0; mi < 4; ++mi)
#pragma unroll
            for (int ni = 0; ni < 4; ++ni)
                acc[mi][ni] = __builtin_amdgcn_mfma_f32_16x16x32_bf16(
                    af[mi], bfr[ni], acc[mi][ni], 0, 0, 0);
    }

#pragma unroll
    for (int mi = 0; mi < 4; ++mi)
#pragma unroll
    for (int ni = 0; ni < 4; ++ni)
#pragma unroll
    for (int q = 0; q < 4; ++q) {
        int row = m_base + wr + mi*16 + l4*4 + q;
        int col = n_base + wc + ni*16 + l15;
        float v = acc[mi][ni][q] + bias[col];
        if (EMODE == 0) {
            C[(size_t)row*ldc + col] = v;
        } else if (EMODE == 1) {
            float s = sigf(v);
            if (col < 1024) {
                UD[(size_t)row*1024 + col] = s;
            } else {
                int jj = col - 1024;
                RX[(size_t)row*1024 + jj] = f2b(s * X[(size_t)row*1024 + jj]);
            }
        } else {
            float hc = tanhf(v);
            float xv = X[(size_t)row*1024 + col];
            float ud = UD[(size_t)row*1024 + col];
            C[(size_t)row*1024 + col] = xv + ud*(hc - xv);
        }
    }
}

// ---------------------------------------------------------------------------
// Persistent cooperative scan: 64 steps per launch, 2 grid.sync per step.
// 256 blocks x 512 threads, 1 block/CU (LDS 130 KB). Recurrence f32.
// gates chunk layout: [(n*64 + tl)][3072].
// ---------------------------------------------------------------------------
__global__ __launch_bounds__(512)
void scan_coop(const float* __restrict__ gates_c,
               const float* __restrict__ WhT,
               const float* __restrict__ prev_ht,
               float* __restrict__ hping,            // [2][32768]
               float* __restrict__ u_buf,
               float* __restrict__ rh_buf,
               unsigned short* __restrict__ htbf,    // [32][512][1024] bf16
               int t0)
{
    cg::grid_group grid = cg::this_grid();
    __shared__ float sh[32768];
    __shared__ float red[512];
    const int tid = threadIdx.x;
    const int bid = blockIdx.x;

    if (t0 == 0) {
        long g = (long)bid*512 + tid;
        if (g < 8192) *(float4*)&hping[g*4] = *(const float4*)&prev_ht[g*4];
        grid.sync();
    }

    for (int tl = 0; tl < 64; ++tl) {
        const int t = t0 + tl;
        const float* hin  = hping + (size_t)(t&1)*32768;
        float*       hout = hping + (size_t)((t+1)&1)*32768;

        // ---------------- phase A: ur = sig(g + h @ Whtg) ----------------
        for (int i = tid*4; i < 32768; i += 2048)
            *(float4*)&sh[i] = *(const float4*)&hin[i];
        __syncthreads();
        {
            const int j  = bid*8 + (tid&7);       // 0..2047
            const int n  = (tid>>3) & 31;
            const int kh = tid>>8;                // split-K 2
            const float* wrow = WhT + (size_t)j*1024 + kh*512;
            const float* hrow = sh + n*1024 + kh*512;
            float acc = 0.f;
#pragma unroll 8
            for (int k = 0; k < 512; k += 4) {
                float4 wv = *(const float4*)&wrow[k];
                float4 hv = *(const float4*)&hrow[k];
                acc = fmaf(hv.x, wv.x, acc);
                acc = fmaf(hv.y, wv.y, acc);
                acc = fmaf(hv.z, wv.z, acc);
                acc = fmaf(hv.w, wv.w, acc);
            }
            if (kh) red[tid & 255] = acc;
            __syncthreads();
            if (!kh) {
                acc += red[tid];
                float g = gates_c[(size_t)(n*64 + tl)*3072 + j];
                float s = sigf(g + acc);
                if (j < 1024) u_buf[n*1024 + j] = s;
                else          rh_buf[n*1024 + (j-1024)] = s * sh[n*1024 + (j-1024)];
            }
        }
        grid.sync();

        // -------- phase B: hc = tanh(g2 + rh @ Wsm); h' = h + u(hc-h) -----
        for (int i = tid*4; i < 32768; i += 2048)
            *(float4*)&sh[i] = *(const float4*)&rh_buf[i];
        __syncthreads();
        {
            const int jb = bid*4 + (tid&3);       // 0..1023
            const int nb = (tid>>2) & 31;
            const int kq = tid>>7;                // split-K 4
            const float* wrow = WhT + (size_t)(2048 + jb)*1024 + kq*256;
            const float* rrow = sh + nb*1024 + kq*256;
            float acc = 0.f;
#pragma unroll 8
            for (int k = 0; k < 256; k += 4) {
                float4 wv = *(const float4*)&wrow[k];
                float4 rv = *(const float4*)&rrow[k];
                acc = fmaf(rv.x, wv.x, acc);
                acc = fmaf(rv.y, wv.y, acc);
                acc = fmaf(rv.z, wv.z, acc);
                acc = fmaf(rv.w, wv.w, acc);
            }
            if (kq) red[(kq-1)*128 + (tid&127)] = acc;
            __syncthreads();
            if (!kq) {
                acc += red[tid] + red[128+tid] + red[256+tid];
                float g  = gates_c[(size_t)(nb*64 + tl)*3072 + 2048 + jb];
                float hc = tanhf(g + acc);
                float h0 = hin[nb*1024 + jb];
                float uu = u_buf[nb*1024 + jb];
                float hn = h0 + uu*(hc - h0);
                hout[nb*1024 + jb] = hn;
                htbf[((size_t)nb*512 + t)*1024 + jb] = f2b(hn);
            }
        }
        grid.sync();
    }
}

__global__ __launch_bounds__(256)
void k_lasth(const float* __restrict__ hping, float* __restrict__ dst)
{
    int i = blockIdx.x*256 + threadIdx.x;     // 32768
    dst[i] = hping[i];
}

// ---------------------------------------------------------------------------
extern "C" void kernel_launch(void* const* d_in, const int* in_sizes, int n_in,
                              void* d_out, int out_size, void* d_ws, size_t ws_size,
                              hipStream_t stream)
{
    const float* x       = (const float*)d_in[0];
    const float* prev_ht = (const float*)d_in[1];
    const float* weight  = (const float*)d_in[2];
    const float* bias    = (const float*)d_in[3];
    float* out = (float*)d_out;
    float* ws  = (float*)d_ws;

    // ws layout (float units):
    unsigned short* WT   = (unsigned short*)ws;            // 6,291,456 f
    float* WhT           = ws + 6291456;                   // 3,145,728 f
    float* chunk         = ws + 9437184;                   // 6,291,456 f
    unsigned short* htbf = (unsigned short*)(ws + 15728640);   // 8,388,608 f
    unsigned short* xbf  = (unsigned short*)(ws + 24117248);   // 8,388,608 f
    float* hping         = ws + 32505856;                  // 65,536 f
    float* u_buf         = ws + 32571392;                  // 32,768 f
    float* rh_buf        = ws + 32604160;                  // 32,768 f
    unsigned short* rxbf = (unsigned short*)(ws + 6291456);    // overlays WhT+chunk
    const size_t needed = (size_t)32636928 * 4;            // 130.5 MB
    if (ws_size < needed) return;

    k_wt <<<dim3(96,32), 256, 0, stream>>>(weight, WT);
    k_wht<<<dim3(48,16), 256, 0, stream>>>(weight, WhT);
    k_xbf<<<16384, 256, 0, stream>>>(x, xbf);

    for (int seg = 0; seg < 8; ++seg) {
        int t0 = seg * 64;
        // gates chunk: [x rows n*512+t0+tl] @ W[:, 0:3072] + bt  (bf16 MFMA)
        gemm_mfma<1,0><<<dim3(24,16), 256, 0, stream>>>(
            xbf, nullptr, WT, chunk, 3072, bias, nullptr, nullptr, nullptr,
            1024, t0);
        const float* gc = chunk;
        void* args[] = { (void*)&gc, (void*)&WhT, (void*)&prev_ht,
                         (void*)&hping, (void*)&u_buf, (void*)&rh_buf,
                         (void*)&htbf, (void*)&t0 };
        hipLaunchCooperativeKernel((void*)scan_coop, dim3(256), dim3(512),
                                   args, 0, stream);
    }

    // depth urd: [x|ht] @ W[:,3072:5120] -> sig -> ud (d_out), rx (bf16)
    gemm_mfma<2,1><<<dim3(16,128), 256, 0, stream>>>(
        xbf, htbf, WT + (size_t)3072*2048, nullptr, 0, bias + 3072,
        x, out, rxbf, 2048, 0);
    // depth hc: [rx|ht] @ W[:,5120:6144] -> tanh -> final out
    gemm_mfma<2,2><<<dim3(8,128), 256, 0, stream>>>(
        rxbf, htbf, WT + (size_t)5120*2048, out, 1024, bias + 5120,
        x, out, nullptr, 2048, 0);

    k_lasth<<<128, 256, 0, stream>>>(hping, out + (size_t)16384*1024);
}

// Round 4
// 60223.352 us; speedup vs baseline: 1.0197x; 1.0197x over previous
//
#include <hip/hip_runtime.h>
#include <cmath>

// ---------------------------------------------------------------------------
// GridGRU on MI355X. Round 4: custom fast grid barrier + LDS pad (scan fix).
// N=32, T=512, D=H=1024. weight (2048,6144) row-major f32, bias 6144.
// ---------------------------------------------------------------------------

#define LDW 6144
typedef float  f32x4 __attribute__((ext_vector_type(4)));
typedef short  s16x8 __attribute__((ext_vector_type(8)));

__device__ __forceinline__ float sigf(float v){ return 1.f/(1.f+__expf(-v)); }
__device__ __forceinline__ unsigned short f2b(float f){
    unsigned u = __float_as_uint(f);
    return (unsigned short)((u + 0x7FFFu + ((u>>16)&1u)) >> 16);
}

// ---- WT[j][k] = bf16(weight[k][j]); j<6144, k<2048 -------------------------
__global__ __launch_bounds__(256)
void k_wt(const float* __restrict__ w, unsigned short* __restrict__ wt)
{
    __shared__ float t[64][65];
    const int j0 = blockIdx.x*64, k0 = blockIdx.y*64;
    for (int i = threadIdx.x; i < 4096; i += 256) {
        int r = i>>6, c = i&63;
        t[r][c] = w[(size_t)(k0+r)*LDW + j0 + c];
    }
    __syncthreads();
    for (int i = threadIdx.x; i < 4096; i += 256) {
        int jr = i>>6, kc = i&63;
        wt[(size_t)(j0+jr)*2048 + k0 + kc] = f2b(t[kc][jr]);
    }
}

// ---- WhT[j][k] = weight[1024+k][j] f32; j<3072, k<1024 ---------------------
__global__ __launch_bounds__(256)
void k_wht(const float* __restrict__ w, float* __restrict__ wht)
{
    __shared__ float t[64][65];
    const int j0 = blockIdx.x*64, k0 = blockIdx.y*64;
    for (int i = threadIdx.x; i < 4096; i += 256) {
        int r = i>>6, c = i&63;
        t[r][c] = w[(size_t)(1024+k0+r)*LDW + j0 + c];
    }
    __syncthreads();
    for (int i = threadIdx.x; i < 4096; i += 256) {
        int jr = i>>6, kc = i&63;
        wht[(size_t)(j0+jr)*1024 + k0 + kc] = t[kc][jr];
    }
}

// ---- x (f32) -> bf16 -------------------------------------------------------
__global__ __launch_bounds__(256)
void k_xbf(const float* __restrict__ x, unsigned short* __restrict__ o)
{
    long i = ((long)blockIdx.x*256 + threadIdx.x)*4;
    float4 v = *(const float4*)&x[i];
    ushort4 r = { f2b(v.x), f2b(v.y), f2b(v.z), f2b(v.w) };
    *(ushort4*)&o[i] = r;
}

// ---------------------------------------------------------------------------
// bf16 MFMA GEMM (unchanged from round 3; passed).
// ---------------------------------------------------------------------------
template<int AMODE, int EMODE>
__global__ __launch_bounds__(256)
void gemm_mfma(const unsigned short* __restrict__ A1,
               const unsigned short* __restrict__ A2,
               const unsigned short* __restrict__ Bw,
               float* __restrict__ C, int ldc,
               const float* __restrict__ bias,
               const float* __restrict__ X,
               float* __restrict__ UD,
               unsigned short* __restrict__ RX,
               int K, int t0)
{
    __shared__ unsigned short Als[128*32];
    __shared__ unsigned short Bls[128*32];
    const int tid = threadIdx.x;
    const int m_base = blockIdx.y*128;
    const int n_base = blockIdx.x*128;
    const int row0 = tid>>2, row1 = row0+64, quad = tid&3;
    const int wv = tid>>6, lane = tid&63;
    const int wr = (wv>>1)*64, wc = (wv&1)*64;
    const int l15 = lane&15, l4 = lane>>4;

    f32x4 acc[4][4] = {};

    for (int k0 = 0; k0 < K; k0 += 32) {
        const int kq = k0 + quad*8;
        s16x8 a0, a1, b0, b1;
        {
            long r0 = m_base + row0, r1 = m_base + row1;
            const unsigned short *p0, *p1;
            if (AMODE == 1) {
                long g0 = (r0>>6)*512 + t0 + (r0&63);
                long g1 = (r1>>6)*512 + t0 + (r1&63);
                p0 = A1 + g0*1024 + kq; p1 = A1 + g1*1024 + kq;
            } else if (AMODE == 2 && k0 >= 1024) {
                p0 = A2 + r0*1024 + (kq-1024); p1 = A2 + r1*1024 + (kq-1024);
            } else {
                p0 = A1 + r0*1024 + kq; p1 = A1 + r1*1024 + kq;
            }
            a0 = *(const s16x8*)p0; a1 = *(const s16x8*)p1;
        }
        b0 = *(const s16x8*)(Bw + (size_t)(n_base+row0)*2048 + kq);
        b1 = *(const s16x8*)(Bw + (size_t)(n_base+row1)*2048 + kq);
        __syncthreads();
        *(s16x8*)&Als[row0*32 + quad*8] = a0;
        *(s16x8*)&Als[row1*32 + quad*8] = a1;
        *(s16x8*)&Bls[row0*32 + quad*8] = b0;
        *(s16x8*)&Bls[row1*32 + quad*8] = b1;
        __syncthreads();
        s16x8 af[4], bfr[4];
#pragma unroll
        for (int i = 0; i < 4; ++i) {
            af[i]  = *(const s16x8*)&Als[(wr + i*16 + l15)*32 + l4*8];
            bfr[i] = *(const s16x8*)&Bls[(wc + i*16 + l15)*32 + l4*8];
        }
#pragma unroll
        for (int mi = 0; mi < 4; ++mi)
#pragma unroll
            for (int ni = 0; ni < 4; ++ni)
                acc[mi][ni] = __builtin_amdgcn_mfma_f32_16x16x32_bf16(
                    af[mi], bfr[ni], acc[mi][ni], 0, 0, 0);
    }

#pragma unroll
    for (int mi = 0; mi < 4; ++mi)
#pragma unroll
    for (int ni = 0; ni < 4; ++ni)
#pragma unroll
    for (int q = 0; q < 4; ++q) {
        int row = m_base + wr + mi*16 + l4*4 + q;
        int col = n_base + wc + ni*16 + l15;
        float v = acc[mi][ni][q] + bias[col];
        if (EMODE == 0) {
            C[(size_t)row*ldc + col] = v;
        } else if (EMODE == 1) {
            float s = sigf(v);
            if (col < 1024) {
                UD[(size_t)row*1024 + col] = s;
            } else {
                int jj = col - 1024;
                RX[(size_t)row*1024 + jj] = f2b(s * X[(size_t)row*1024 + jj]);
            }
        } else {
            float hc = tanhf(v);
            float xv = X[(size_t)row*1024 + col];
            float ud = UD[(size_t)row*1024 + col];
            C[(size_t)row*1024 + col] = xv + ud*(hc - xv);
        }
    }
}

// ---------------------------------------------------------------------------
// Custom sense-reversing grid barrier (agent scope).
// bar[0] = arrive counter, bar[16] = generation (64B apart).
// ---------------------------------------------------------------------------
__device__ __forceinline__ void gridbar(unsigned* cnt, unsigned* genp,
                                        unsigned nb, unsigned& mygen)
{
    __syncthreads();
    if (threadIdx.x == 0) {
        __threadfence();   // release: make this block's writes agent-visible
        unsigned old = __hip_atomic_fetch_add(cnt, 1u, __ATOMIC_ACQ_REL,
                                              __HIP_MEMORY_SCOPE_AGENT);
        if (old == nb - 1u) {
            __hip_atomic_store(cnt, 0u, __ATOMIC_RELAXED,
                               __HIP_MEMORY_SCOPE_AGENT);
            __hip_atomic_store(genp, mygen + 1u, __ATOMIC_RELEASE,
                               __HIP_MEMORY_SCOPE_AGENT);
        } else {
            while (__hip_atomic_load(genp, __ATOMIC_ACQUIRE,
                                     __HIP_MEMORY_SCOPE_AGENT) == mygen)
                __builtin_amdgcn_s_sleep(2);
        }
        mygen += 1u;
        __threadfence();   // acquire: invalidate stale cached lines
    }
    __syncthreads();
}

// ---------------------------------------------------------------------------
// Persistent cooperative scan: 64 steps/launch, 2 custom barriers/step.
// 256 blocks x 512 threads, 1 block/CU. LDS h tile padded [32][1028].
// ---------------------------------------------------------------------------
__global__ __launch_bounds__(512)
void scan_coop(const float* __restrict__ gates_c,
               const float* __restrict__ WhT,
               const float* __restrict__ prev_ht,
               float* __restrict__ hping,            // [2][32768]
               float* __restrict__ u_buf,
               float* __restrict__ rh_buf,
               unsigned short* __restrict__ htbf,    // [32][512][1024] bf16
               unsigned* __restrict__ bar,
               int t0)
{
    __shared__ float sh[32*1028];                    // padded: row stride 1028
    __shared__ float red[512];
    const int tid = threadIdx.x;
    const int bid = blockIdx.x;
    unsigned* cnt  = bar;
    unsigned* genp = bar + 16;
    unsigned mygen = __hip_atomic_load(genp, __ATOMIC_RELAXED,
                                       __HIP_MEMORY_SCOPE_AGENT);

    if (t0 == 0) {
        long g = (long)bid*512 + tid;
        if (g < 8192) *(float4*)&hping[g*4] = *(const float4*)&prev_ht[g*4];
        gridbar(cnt, genp, 256, mygen);
    }

    for (int tl = 0; tl < 64; ++tl) {
        const int t = t0 + tl;
        const float* hin  = hping + (size_t)(t&1)*32768;
        float*       hout = hping + (size_t)((t+1)&1)*32768;

        // ---------------- phase A: ur = sig(g + h @ Whtg) ----------------
        for (int i = tid*4; i < 32768; i += 2048) {
            int n = i >> 10, k = i & 1023;
            *(float4*)&sh[n*1028 + k] = *(const float4*)&hin[i];
        }
        __syncthreads();
        {
            const int j  = bid*8 + (tid&7);       // 0..2047
            const int n  = (tid>>3) & 31;
            const int kh = tid>>8;                // split-K 2
            const float* wrow = WhT + (size_t)j*1024 + kh*512;
            const float* hrow = sh + n*1028 + kh*512;
            float acc = 0.f;
#pragma unroll 8
            for (int k = 0; k < 512; k += 4) {
                float4 wv = *(const float4*)&wrow[k];
                float4 hv = *(const float4*)&hrow[k];
                acc = fmaf(hv.x, wv.x, acc);
                acc = fmaf(hv.y, wv.y, acc);
                acc = fmaf(hv.z, wv.z, acc);
                acc = fmaf(hv.w, wv.w, acc);
            }
            if (kh) red[tid & 255] = acc;
            __syncthreads();
            if (!kh) {
                acc += red[tid];
                float g = gates_c[(size_t)(n*64 + tl)*3072 + j];
                float s = sigf(g + acc);
                if (j < 1024) u_buf[n*1024 + j] = s;
                else          rh_buf[n*1024 + (j-1024)] = s * sh[n*1028 + (j-1024)];
            }
        }
        gridbar(cnt, genp, 256, mygen);

        // -------- phase B: hc = tanh(g2 + rh @ Wsm); h' = h + u(hc-h) -----
        for (int i = tid*4; i < 32768; i += 2048) {
            int n = i >> 10, k = i & 1023;
            *(float4*)&sh[n*1028 + k] = *(const float4*)&rh_buf[i];
        }
        __syncthreads();
        {
            const int jb = bid*4 + (tid&3);       // 0..1023
            const int nb = (tid>>2) & 31;
            const int kq = tid>>7;                // split-K 4
            const float* wrow = WhT + (size_t)(2048 + jb)*1024 + kq*256;
            const float* rrow = sh + nb*1028 + kq*256;
            float acc = 0.f;
#pragma unroll 8
            for (int k = 0; k < 256; k += 4) {
                float4 wv = *(const float4*)&wrow[k];
                float4 rv = *(const float4*)&rrow[k];
                acc = fmaf(rv.x, wv.x, acc);
                acc = fmaf(rv.y, wv.y, acc);
                acc = fmaf(rv.z, wv.z, acc);
                acc = fmaf(rv.w, wv.w, acc);
            }
            if (kq) red[(kq-1)*128 + (tid&127)] = acc;
            __syncthreads();
            if (!kq) {
                acc += red[tid] + red[128+tid] + red[256+tid];
                float g  = gates_c[(size_t)(nb*64 + tl)*3072 + 2048 + jb];
                float hc = tanhf(g + acc);
                float h0 = hin[nb*1024 + jb];
                float uu = u_buf[nb*1024 + jb];
                float hn = h0 + uu*(hc - h0);
                hout[nb*1024 + jb] = hn;
                htbf[((size_t)nb*512 + t)*1024 + jb] = f2b(hn);
            }
        }
        gridbar(cnt, genp, 256, mygen);
    }
}

__global__ __launch_bounds__(256)
void k_lasth(const float* __restrict__ hping, float* __restrict__ dst)
{
    int i = blockIdx.x*256 + threadIdx.x;     // 32768
    dst[i] = hping[i];
}

// ---------------------------------------------------------------------------
extern "C" void kernel_launch(void* const* d_in, const int* in_sizes, int n_in,
                              void* d_out, int out_size, void* d_ws, size_t ws_size,
                              hipStream_t stream)
{
    const float* x       = (const float*)d_in[0];
    const float* prev_ht = (const float*)d_in[1];
    const float* weight  = (const float*)d_in[2];
    const float* bias    = (const float*)d_in[3];
    float* out = (float*)d_out;
    float* ws  = (float*)d_ws;

    // ws layout (float units):
    unsigned short* WT   = (unsigned short*)ws;                // 6,291,456 f
    float* WhT           = ws + 6291456;                       // 3,145,728 f
    float* chunk         = ws + 9437184;                       // 6,291,456 f
    unsigned short* htbf = (unsigned short*)(ws + 15728640);   // 8,388,608 f
    unsigned short* xbf  = (unsigned short*)(ws + 24117248);   // 8,388,608 f
    float* hping         = ws + 32505856;                      // 65,536 f
    float* u_buf         = ws + 32571392;                      // 32,768 f
    float* rh_buf        = ws + 32604160;                      // 32,768 f
    unsigned* bar        = (unsigned*)(ws + 32636928);         // 32 u32
    unsigned short* rxbf = (unsigned short*)(ws + 6291456);    // overlays WhT+chunk
    const size_t needed = (size_t)(32636928 + 32) * 4;         // 130.5 MB
    if (ws_size < needed) return;

    hipMemsetAsync(bar, 0, 128, stream);
    k_wt <<<dim3(96,32), 256, 0, stream>>>(weight, WT);
    k_wht<<<dim3(48,16), 256, 0, stream>>>(weight, WhT);
    k_xbf<<<16384, 256, 0, stream>>>(x, xbf);

    for (int seg = 0; seg < 8; ++seg) {
        int t0 = seg * 64;
        gemm_mfma<1,0><<<dim3(24,16), 256, 0, stream>>>(
            xbf, nullptr, WT, chunk, 3072, bias, nullptr, nullptr, nullptr,
            1024, t0);
        const float* gc = chunk;
        void* args[] = { (void*)&gc, (void*)&WhT, (void*)&prev_ht,
                         (void*)&hping, (void*)&u_buf, (void*)&rh_buf,
                         (void*)&htbf, (void*)&bar, (void*)&t0 };
        hipLaunchCooperativeKernel((void*)scan_coop, dim3(256), dim3(512),
                                   args, 0, stream);
    }

    // depth urd: [x|ht] @ W[:,3072:5120] -> sig -> ud (d_out), rx (bf16)
    gemm_mfma<2,1><<<dim3(16,128), 256, 0, stream>>>(
        xbf, htbf, WT + (size_t)3072*2048, nullptr, 0, bias + 3072,
        x, out, rxbf, 2048, 0);
    // depth hc: [rx|ht] @ W[:,5120:6144] -> tanh -> final out
    gemm_mfma<2,2><<<dim3(8,128), 256, 0, stream>>>(
        rxbf, htbf, WT + (size_t)5120*2048, out, 1024, bias + 5120,
        x, out, nullptr, 2048, 0);

    k_lasth<<<128, 256, 0, stream>>>(hping, out + (size_t)16384*1024);
}

// Round 5
// 28271.274 us; speedup vs baseline: 2.1722x; 2.1302x over previous
//
#include <hip/hip_runtime.h>
#include <cmath>

// ---------------------------------------------------------------------------
// GridGRU on MI355X. Round 5: fence-free scan sync.
// Shared per-step state (h/u/rh) moves via sc0+sc1 (system-coherent, L2-bypass)
// loads/stores; barrier = monotonic relaxed system atomic counter. No cache
// flushes anywhere in the persistent kernel -> W stays hot in L1/L2.
// N=32, T=512, D=H=1024. weight (2048,6144) row-major f32, bias 6144.
// ---------------------------------------------------------------------------

#define LDW 6144
typedef float  f32x4 __attribute__((ext_vector_type(4)));
typedef short  s16x8 __attribute__((ext_vector_type(8)));

__device__ __forceinline__ float sigf(float v){ return 1.f/(1.f+__expf(-v)); }
__device__ __forceinline__ unsigned short f2b(float f){
    unsigned u = __float_as_uint(f);
    return (unsigned short)((u + 0x7FFFu + ((u>>16)&1u)) >> 16);
}

// ---- system-coherent (L2-bypass) access helpers ---------------------------
__device__ __forceinline__ void st_sc1(float* p, float v){
    asm volatile("global_store_dword %0, %1, off sc0 sc1"
                 :: "v"(p), "v"(v) : "memory");
}
__device__ __forceinline__ void st_sc4(float* p, f32x4 v){
    asm volatile("global_store_dwordx4 %0, %1, off sc0 sc1"
                 :: "v"(p), "v"(v) : "memory");
}

// ---- WT[j][k] = bf16(weight[k][j]); j<6144, k<2048 -------------------------
__global__ __launch_bounds__(256)
void k_wt(const float* __restrict__ w, unsigned short* __restrict__ wt)
{
    __shared__ float t[64][65];
    const int j0 = blockIdx.x*64, k0 = blockIdx.y*64;
    for (int i = threadIdx.x; i < 4096; i += 256) {
        int r = i>>6, c = i&63;
        t[r][c] = w[(size_t)(k0+r)*LDW + j0 + c];
    }
    __syncthreads();
    for (int i = threadIdx.x; i < 4096; i += 256) {
        int jr = i>>6, kc = i&63;
        wt[(size_t)(j0+jr)*2048 + k0 + kc] = f2b(t[kc][jr]);
    }
}

// ---- WhT[j][k] = weight[1024+k][j] f32; j<3072, k<1024 ---------------------
__global__ __launch_bounds__(256)
void k_wht(const float* __restrict__ w, float* __restrict__ wht)
{
    __shared__ float t[64][65];
    const int j0 = blockIdx.x*64, k0 = blockIdx.y*64;
    for (int i = threadIdx.x; i < 4096; i += 256) {
        int r = i>>6, c = i&63;
        t[r][c] = w[(size_t)(1024+k0+r)*LDW + j0 + c];
    }
    __syncthreads();
    for (int i = threadIdx.x; i < 4096; i += 256) {
        int jr = i>>6, kc = i&63;
        wht[(size_t)(j0+jr)*1024 + k0 + kc] = t[kc][jr];
    }
}

// ---- x (f32) -> bf16 -------------------------------------------------------
__global__ __launch_bounds__(256)
void k_xbf(const float* __restrict__ x, unsigned short* __restrict__ o)
{
    long i = ((long)blockIdx.x*256 + threadIdx.x)*4;
    float4 v = *(const float4*)&x[i];
    ushort4 r = { f2b(v.x), f2b(v.y), f2b(v.z), f2b(v.w) };
    *(ushort4*)&o[i] = r;
}

// ---------------------------------------------------------------------------
// bf16 MFMA GEMM (unchanged; validated rounds 3-4).
// ---------------------------------------------------------------------------
template<int AMODE, int EMODE>
__global__ __launch_bounds__(256)
void gemm_mfma(const unsigned short* __restrict__ A1,
               const unsigned short* __restrict__ A2,
               const unsigned short* __restrict__ Bw,
               float* __restrict__ C, int ldc,
               const float* __restrict__ bias,
               const float* __restrict__ X,
               float* __restrict__ UD,
               unsigned short* __restrict__ RX,
               int K, int t0)
{
    __shared__ unsigned short Als[128*32];
    __shared__ unsigned short Bls[128*32];
    const int tid = threadIdx.x;
    const int m_base = blockIdx.y*128;
    const int n_base = blockIdx.x*128;
    const int row0 = tid>>2, row1 = row0+64, quad = tid&3;
    const int wv = tid>>6, lane = tid&63;
    const int wr = (wv>>1)*64, wc = (wv&1)*64;
    const int l15 = lane&15, l4 = lane>>4;

    f32x4 acc[4][4] = {};

    for (int k0 = 0; k0 < K; k0 += 32) {
        const int kq = k0 + quad*8;
        s16x8 a0, a1, b0, b1;
        {
            long r0 = m_base + row0, r1 = m_base + row1;
            const unsigned short *p0, *p1;
            if (AMODE == 1) {
                long g0 = (r0>>6)*512 + t0 + (r0&63);
                long g1 = (r1>>6)*512 + t0 + (r1&63);
                p0 = A1 + g0*1024 + kq; p1 = A1 + g1*1024 + kq;
            } else if (AMODE == 2 && k0 >= 1024) {
                p0 = A2 + r0*1024 + (kq-1024); p1 = A2 + r1*1024 + (kq-1024);
            } else {
                p0 = A1 + r0*1024 + kq; p1 = A1 + r1*1024 + kq;
            }
            a0 = *(const s16x8*)p0; a1 = *(const s16x8*)p1;
        }
        b0 = *(const s16x8*)(Bw + (size_t)(n_base+row0)*2048 + kq);
        b1 = *(const s16x8*)(Bw + (size_t)(n_base+row1)*2048 + kq);
        __syncthreads();
        *(s16x8*)&Als[row0*32 + quad*8] = a0;
        *(s16x8*)&Als[row1*32 + quad*8] = a1;
        *(s16x8*)&Bls[row0*32 + quad*8] = b0;
        *(s16x8*)&Bls[row1*32 + quad*8] = b1;
        __syncthreads();
        s16x8 af[4], bfr[4];
#pragma unroll
        for (int i = 0; i < 4; ++i) {
            af[i]  = *(const s16x8*)&Als[(wr + i*16 + l15)*32 + l4*8];
            bfr[i] = *(const s16x8*)&Bls[(wc + i*16 + l15)*32 + l4*8];
        }
#pragma unroll
        for (int mi = 0; mi < 4; ++mi)
#pragma unroll
            for (int ni = 0; ni < 4; ++ni)
                acc[mi][ni] = __builtin_amdgcn_mfma_f32_16x16x32_bf16(
                    af[mi], bfr[ni], acc[mi][ni], 0, 0, 0);
    }

#pragma unroll
    for (int mi = 0; mi < 4; ++mi)
#pragma unroll
    for (int ni = 0; ni < 4; ++ni)
#pragma unroll
    for (int q = 0; q < 4; ++q) {
        int row = m_base + wr + mi*16 + l4*4 + q;
        int col = n_base + wc + ni*16 + l15;
        float v = acc[mi][ni][q] + bias[col];
        if (EMODE == 0) {
            C[(size_t)row*ldc + col] = v;
        } else if (EMODE == 1) {
            float s = sigf(v);
            if (col < 1024) {
                UD[(size_t)row*1024 + col] = s;
            } else {
                int jj = col - 1024;
                RX[(size_t)row*1024 + jj] = f2b(s * X[(size_t)row*1024 + jj]);
            }
        } else {
            float hc = tanhf(v);
            float xv = X[(size_t)row*1024 + col];
            float ud = UD[(size_t)row*1024 + col];
            C[(size_t)row*1024 + col] = xv + ud*(hc - xv);
        }
    }
}

// ---------------------------------------------------------------------------
// Monotonic fence-free grid barrier. cnt never resets; each block has a
// local barrier index. __syncthreads() drains vmcnt (all waves' sc-stores
// complete) before the arrive; spin is relaxed system loads (no cache ops).
// ---------------------------------------------------------------------------
__device__ __forceinline__ void gridbar(unsigned* cnt, unsigned nb, unsigned& bidx)
{
    __syncthreads();
    ++bidx;
    if (threadIdx.x == 0) {
        __hip_atomic_fetch_add(cnt, 1u, __ATOMIC_RELAXED,
                               __HIP_MEMORY_SCOPE_SYSTEM);
        const unsigned target = nb * bidx;
        while (__hip_atomic_load(cnt, __ATOMIC_RELAXED,
                                 __HIP_MEMORY_SCOPE_SYSTEM) < target)
            __builtin_amdgcn_s_sleep(1);
    }
    __syncthreads();
}

// ---------------------------------------------------------------------------
// Persistent scan: 64 steps/launch, 2 barriers/step, 129 barriers/launch.
// 256 blocks x 512 threads, 1 block/CU. LDS tile padded [32][1028].
// h/u/rh exchanged via sc0+sc1 accesses only (never cached in L1/L2).
// ---------------------------------------------------------------------------
__global__ __launch_bounds__(512)
void scan_coop(const float* __restrict__ gates_c,
               const float* __restrict__ WhT,
               const float* __restrict__ prev_ht,
               float* __restrict__ hping,            // [2][32768], sc-only
               float* __restrict__ u_buf,            // sc-only
               float* __restrict__ rh_buf,           // sc-only
               unsigned short* __restrict__ htbf,    // [32][512][1024] bf16
               unsigned* __restrict__ bar,
               int t0, int bidx0)
{
    __shared__ float sh[32*1028];
    __shared__ float red[512];
    const int tid = threadIdx.x;
    const int bid = blockIdx.x;
    unsigned bidx = (unsigned)bidx0;

    if (t0 == 0) {
        long g = (long)bid*512 + tid;
        if (g < 8192) {
            f32x4 v = *(const f32x4*)&prev_ht[g*4];
            st_sc4(&hping[g*4], v);
        }
    }
    gridbar(bar, 256, bidx);     // unconditional: 129 barriers per launch

    for (int tl = 0; tl < 64; ++tl) {
        const int t = t0 + tl;
        const float* hin  = hping + (size_t)(t&1)*32768;
        float*       hout = hping + (size_t)((t+1)&1)*32768;

        // ---- stage h (sc loads, 2 rounds x 8 float4/thread) --------------
#pragma unroll
        for (int r8 = 0; r8 < 2; ++r8) {
            f32x4 v[8];
#pragma unroll
            for (int q = 0; q < 8; ++q) {
                const float* p = &hin[tid*4 + (r8*8+q)*2048];
                asm volatile("global_load_dwordx4 %0, %1, off sc0 sc1"
                             : "=v"(v[q]) : "v"(p));
            }
            asm volatile("s_waitcnt vmcnt(0)" ::: "memory");
            __builtin_amdgcn_sched_barrier(0);
#pragma unroll
            for (int q = 0; q < 8; ++q) {
                int i = tid*4 + (r8*8+q)*2048;
                int n = i >> 10, k = i & 1023;
                *(f32x4*)&sh[n*1028 + k] = v[q];
            }
        }
        __syncthreads();

        // ---------------- phase A: ur = sig(g + h @ Whtg) ----------------
        {
            const int j  = bid*8 + (tid&7);       // 0..2047
            const int n  = (tid>>3) & 31;
            const int kh = tid>>8;                // split-K 2
            const float* wrow = WhT + (size_t)j*1024 + kh*512;
            const float* hrow = sh + n*1028 + kh*512;
            float acc = 0.f;
#pragma unroll 8
            for (int k = 0; k < 512; k += 4) {
                float4 wv = *(const float4*)&wrow[k];
                float4 hv = *(const float4*)&hrow[k];
                acc = fmaf(hv.x, wv.x, acc);
                acc = fmaf(hv.y, wv.y, acc);
                acc = fmaf(hv.z, wv.z, acc);
                acc = fmaf(hv.w, wv.w, acc);
            }
            if (kh) red[tid & 255] = acc;
            __syncthreads();
            if (!kh) {
                acc += red[tid];
                float g = gates_c[(size_t)(n*64 + tl)*3072 + j];
                float s = sigf(g + acc);
                if (j < 1024) st_sc1(&u_buf[n*1024 + j], s);
                else st_sc1(&rh_buf[n*1024 + (j-1024)], s * sh[n*1028 + (j-1024)]);
            }
        }
        gridbar(bar, 256, bidx);

        // ---- stage rh (sc loads) ----------------------------------------
#pragma unroll
        for (int r8 = 0; r8 < 2; ++r8) {
            f32x4 v[8];
#pragma unroll
            for (int q = 0; q < 8; ++q) {
                const float* p = &rh_buf[tid*4 + (r8*8+q)*2048];
                asm volatile("global_load_dwordx4 %0, %1, off sc0 sc1"
                             : "=v"(v[q]) : "v"(p));
            }
            asm volatile("s_waitcnt vmcnt(0)" ::: "memory");
            __builtin_amdgcn_sched_barrier(0);
#pragma unroll
            for (int q = 0; q < 8; ++q) {
                int i = tid*4 + (r8*8+q)*2048;
                int n = i >> 10, k = i & 1023;
                *(f32x4*)&sh[n*1028 + k] = v[q];
            }
        }
        __syncthreads();

        // -------- phase B: hc = tanh(g2 + rh @ Wsm); h' = h + u(hc-h) -----
        {
            const int jb = bid*4 + (tid&3);       // 0..1023
            const int nb = (tid>>2) & 31;
            const int kq = tid>>7;                // split-K 4
            float h0, uu;
            {
                const float* ph = &hin[nb*1024 + jb];
                const float* pu = &u_buf[nb*1024 + jb];
                asm volatile("global_load_dword %0, %1, off sc0 sc1"
                             : "=v"(h0) : "v"(ph));
                asm volatile("global_load_dword %0, %1, off sc0 sc1"
                             : "=v"(uu) : "v"(pu));
            }
            const float* wrow = WhT + (size_t)(2048 + jb)*1024 + kq*256;
            const float* rrow = sh + nb*1028 + kq*256;
            float acc = 0.f;
#pragma unroll 8
            for (int k = 0; k < 256; k += 4) {
                float4 wv = *(const float4*)&wrow[k];
                float4 rv = *(const float4*)&rrow[k];
                acc = fmaf(rv.x, wv.x, acc);
                acc = fmaf(rv.y, wv.y, acc);
                acc = fmaf(rv.z, wv.z, acc);
                acc = fmaf(rv.w, wv.w, acc);
            }
            if (kq) red[(kq-1)*128 + (tid&127)] = acc;
            asm volatile("s_waitcnt vmcnt(0)" ::: "memory");
            __builtin_amdgcn_sched_barrier(0);
            __syncthreads();
            if (!kq) {
                acc += red[tid] + red[128+tid] + red[256+tid];
                float g  = gates_c[(size_t)(nb*64 + tl)*3072 + 2048 + jb];
                float hc = tanhf(g + acc);
                float hn = h0 + uu*(hc - h0);
                st_sc1(&hout[nb*1024 + jb], hn);
                htbf[((size_t)nb*512 + t)*1024 + jb] = f2b(hn);   // plain store
            }
        }
        gridbar(bar, 256, bidx);
    }
}

__global__ __launch_bounds__(256)
void k_lasth(const float* __restrict__ hping, float* __restrict__ dst)
{
    int i = blockIdx.x*256 + threadIdx.x;     // 32768
    dst[i] = hping[i];
}

// ---------------------------------------------------------------------------
extern "C" void kernel_launch(void* const* d_in, const int* in_sizes, int n_in,
                              void* d_out, int out_size, void* d_ws, size_t ws_size,
                              hipStream_t stream)
{
    const float* x       = (const float*)d_in[0];
    const float* prev_ht = (const float*)d_in[1];
    const float* weight  = (const float*)d_in[2];
    const float* bias    = (const float*)d_in[3];
    float* out = (float*)d_out;
    float* ws  = (float*)d_ws;

    // ws layout (float units):
    unsigned short* WT   = (unsigned short*)ws;                // 6,291,456 f
    float* WhT           = ws + 6291456;                       // 3,145,728 f
    float* chunk         = ws + 9437184;                       // 6,291,456 f
    unsigned short* htbf = (unsigned short*)(ws + 15728640);   // 8,388,608 f
    unsigned short* xbf  = (unsigned short*)(ws + 24117248);   // 8,388,608 f
    float* hping         = ws + 32505856;                      // 65,536 f
    float* u_buf         = ws + 32571392;                      // 32,768 f
    float* rh_buf        = ws + 32604160;                      // 32,768 f
    unsigned* bar        = (unsigned*)(ws + 32636928);         // 32 u32
    unsigned short* rxbf = (unsigned short*)(ws + 6291456);    // overlays WhT+chunk
    const size_t needed = (size_t)(32636928 + 32) * 4;         // 130.5 MB
    if (ws_size < needed) return;

    hipMemsetAsync(bar, 0, 128, stream);
    k_wt <<<dim3(96,32), 256, 0, stream>>>(weight, WT);
    k_wht<<<dim3(48,16), 256, 0, stream>>>(weight, WhT);
    k_xbf<<<16384, 256, 0, stream>>>(x, xbf);

    for (int seg = 0; seg < 8; ++seg) {
        int t0 = seg * 64;
        int bidx0 = seg * 129;
        gemm_mfma<1,0><<<dim3(24,16), 256, 0, stream>>>(
            xbf, nullptr, WT, chunk, 3072, bias, nullptr, nullptr, nullptr,
            1024, t0);
        const float* gc = chunk;
        void* args[] = { (void*)&gc, (void*)&WhT, (void*)&prev_ht,
                         (void*)&hping, (void*)&u_buf, (void*)&rh_buf,
                         (void*)&htbf, (void*)&bar, (void*)&t0, (void*)&bidx0 };
        hipLaunchCooperativeKernel((void*)scan_coop, dim3(256), dim3(512),
                                   args, 0, stream);
    }

    // depth urd: [x|ht] @ W[:,3072:5120] -> sig -> ud (d_out), rx (bf16)
    gemm_mfma<2,1><<<dim3(16,128), 256, 0, stream>>>(
        xbf, htbf, WT + (size_t)3072*2048, nullptr, 0, bias + 3072,
        x, out, rxbf, 2048, 0);
    // depth hc: [rx|ht] @ W[:,5120:6144] -> tanh -> final out
    gemm_mfma<2,2><<<dim3(8,128), 256, 0, stream>>>(
        rxbf, htbf, WT + (size_t)5120*2048, out, 1024, bias + 5120,
        x, out, nullptr, 2048, 0);

    k_lasth<<<128, 256, 0, stream>>>(hping, out + (size_t)16384*1024);
}

// Round 6
// 26155.493 us; speedup vs baseline: 2.3479x; 1.0809x over previous
//
#include <hip/hip_runtime.h>
#include <cmath>

// ---------------------------------------------------------------------------
// GridGRU on MI355X. Round 6: flag-array grid barrier (no RMW contention).
// h/u/rh exchanged via sc0+sc1 (system-coherent, cache-bypass) accesses;
// barrier = per-block monotonic flag lines + all-peer polling.
// N=32, T=512, D=H=1024. weight (2048,6144) row-major f32, bias 6144.
// ---------------------------------------------------------------------------

#define LDW 6144
typedef float  f32x4 __attribute__((ext_vector_type(4)));
typedef short  s16x8 __attribute__((ext_vector_type(8)));

__device__ __forceinline__ float sigf(float v){ return 1.f/(1.f+__expf(-v)); }
__device__ __forceinline__ unsigned short f2b(float f){
    unsigned u = __float_as_uint(f);
    return (unsigned short)((u + 0x7FFFu + ((u>>16)&1u)) >> 16);
}

// ---- system-coherent (cache-bypass) access helpers ------------------------
__device__ __forceinline__ void st_sc1(float* p, float v){
    asm volatile("global_store_dword %0, %1, off sc0 sc1"
                 :: "v"(p), "v"(v) : "memory");
}
__device__ __forceinline__ void st_sc4(float* p, f32x4 v){
    asm volatile("global_store_dwordx4 %0, %1, off sc0 sc1"
                 :: "v"(p), "v"(v) : "memory");
}
__device__ __forceinline__ void st_sc_u32(unsigned* p, unsigned v){
    asm volatile("global_store_dword %0, %1, off sc0 sc1"
                 :: "v"(p), "v"(v) : "memory");
}
__device__ __forceinline__ unsigned ld_sc_u32(const unsigned* p){
    unsigned v;
    asm volatile("global_load_dword %0, %1, off sc0 sc1\n\t"
                 "s_waitcnt vmcnt(0)"
                 : "=v"(v) : "v"(p) : "memory");
    return v;
}

// ---- WT[j][k] = bf16(weight[k][j]); j<6144, k<2048 -------------------------
__global__ __launch_bounds__(256)
void k_wt(const float* __restrict__ w, unsigned short* __restrict__ wt)
{
    __shared__ float t[64][65];
    const int j0 = blockIdx.x*64, k0 = blockIdx.y*64;
    for (int i = threadIdx.x; i < 4096; i += 256) {
        int r = i>>6, c = i&63;
        t[r][c] = w[(size_t)(k0+r)*LDW + j0 + c];
    }
    __syncthreads();
    for (int i = threadIdx.x; i < 4096; i += 256) {
        int jr = i>>6, kc = i&63;
        wt[(size_t)(j0+jr)*2048 + k0 + kc] = f2b(t[kc][jr]);
    }
}

// ---- WhT[j][k] = weight[1024+k][j] f32; j<3072, k<1024 ---------------------
__global__ __launch_bounds__(256)
void k_wht(const float* __restrict__ w, float* __restrict__ wht)
{
    __shared__ float t[64][65];
    const int j0 = blockIdx.x*64, k0 = blockIdx.y*64;
    for (int i = threadIdx.x; i < 4096; i += 256) {
        int r = i>>6, c = i&63;
        t[r][c] = w[(size_t)(1024+k0+r)*LDW + j0 + c];
    }
    __syncthreads();
    for (int i = threadIdx.x; i < 4096; i += 256) {
        int jr = i>>6, kc = i&63;
        wht[(size_t)(j0+jr)*1024 + k0 + kc] = t[kc][jr];
    }
}

// ---- x (f32) -> bf16 -------------------------------------------------------
__global__ __launch_bounds__(256)
void k_xbf(const float* __restrict__ x, unsigned short* __restrict__ o)
{
    long i = ((long)blockIdx.x*256 + threadIdx.x)*4;
    float4 v = *(const float4*)&x[i];
    ushort4 r = { f2b(v.x), f2b(v.y), f2b(v.z), f2b(v.w) };
    *(ushort4*)&o[i] = r;
}

// ---------------------------------------------------------------------------
// bf16 MFMA GEMM (unchanged; validated rounds 3-5).
// ---------------------------------------------------------------------------
template<int AMODE, int EMODE>
__global__ __launch_bounds__(256)
void gemm_mfma(const unsigned short* __restrict__ A1,
               const unsigned short* __restrict__ A2,
               const unsigned short* __restrict__ Bw,
               float* __restrict__ C, int ldc,
               const float* __restrict__ bias,
               const float* __restrict__ X,
               float* __restrict__ UD,
               unsigned short* __restrict__ RX,
               int K, int t0)
{
    __shared__ unsigned short Als[128*32];
    __shared__ unsigned short Bls[128*32];
    const int tid = threadIdx.x;
    const int m_base = blockIdx.y*128;
    const int n_base = blockIdx.x*128;
    const int row0 = tid>>2, row1 = row0+64, quad = tid&3;
    const int wv = tid>>6, lane = tid&63;
    const int wr = (wv>>1)*64, wc = (wv&1)*64;
    const int l15 = lane&15, l4 = lane>>4;

    f32x4 acc[4][4] = {};

    for (int k0 = 0; k0 < K; k0 += 32) {
        const int kq = k0 + quad*8;
        s16x8 a0, a1, b0, b1;
        {
            long r0 = m_base + row0, r1 = m_base + row1;
            const unsigned short *p0, *p1;
            if (AMODE == 1) {
                long g0 = (r0>>6)*512 + t0 + (r0&63);
                long g1 = (r1>>6)*512 + t0 + (r1&63);
                p0 = A1 + g0*1024 + kq; p1 = A1 + g1*1024 + kq;
            } else if (AMODE == 2 && k0 >= 1024) {
                p0 = A2 + r0*1024 + (kq-1024); p1 = A2 + r1*1024 + (kq-1024);
            } else {
                p0 = A1 + r0*1024 + kq; p1 = A1 + r1*1024 + kq;
            }
            a0 = *(const s16x8*)p0; a1 = *(const s16x8*)p1;
        }
        b0 = *(const s16x8*)(Bw + (size_t)(n_base+row0)*2048 + kq);
        b1 = *(const s16x8*)(Bw + (size_t)(n_base+row1)*2048 + kq);
        __syncthreads();
        *(s16x8*)&Als[row0*32 + quad*8] = a0;
        *(s16x8*)&Als[row1*32 + quad*8] = a1;
        *(s16x8*)&Bls[row0*32 + quad*8] = b0;
        *(s16x8*)&Bls[row1*32 + quad*8] = b1;
        __syncthreads();
        s16x8 af[4], bfr[4];
#pragma unroll
        for (int i = 0; i < 4; ++i) {
            af[i]  = *(const s16x8*)&Als[(wr + i*16 + l15)*32 + l4*8];
            bfr[i] = *(const s16x8*)&Bls[(wc + i*16 + l15)*32 + l4*8];
        }
#pragma unroll
        for (int mi = 0; mi < 4; ++mi)
#pragma unroll
            for (int ni = 0; ni < 4; ++ni)
                acc[mi][ni] = __builtin_amdgcn_mfma_f32_16x16x32_bf16(
                    af[mi], bfr[ni], acc[mi][ni], 0, 0, 0);
    }

#pragma unroll
    for (int mi = 0; mi < 4; ++mi)
#pragma unroll
    for (int ni = 0; ni < 4; ++ni)
#pragma unroll
    for (int q = 0; q < 4; ++q) {
        int row = m_base + wr + mi*16 + l4*4 + q;
        int col = n_base + wc + ni*16 + l15;
        float v = acc[mi][ni][q] + bias[col];
        if (EMODE == 0) {
            C[(size_t)row*ldc + col] = v;
        } else if (EMODE == 1) {
            float s = sigf(v);
            if (col < 1024) {
                UD[(size_t)row*1024 + col] = s;
            } else {
                int jj = col - 1024;
                RX[(size_t)row*1024 + jj] = f2b(s * X[(size_t)row*1024 + jj]);
            }
        } else {
            float hc = tanhf(v);
            float xv = X[(size_t)row*1024 + col];
            float ud = UD[(size_t)row*1024 + col];
            C[(size_t)row*1024 + col] = xv + ud*(hc - xv);
        }
    }
}

// ---------------------------------------------------------------------------
// Flag-array grid barrier: flags[b*32] is block b's monotonic arrival count.
// Arrival: one sc store to own line (no RMW, no contention).
// Wait: threads 0..255 poll one peer flag each until >= target.
// __syncthreads() at entry drains vmcnt (data stores visible) before arrive.
// ---------------------------------------------------------------------------
__device__ __forceinline__ void flagbar(unsigned* flags, unsigned& bidx)
{
    __syncthreads();                 // all waves' sc data-stores drained
    ++bidx;
    const int tid = threadIdx.x;
    if (tid == 0) st_sc_u32(&flags[(unsigned)blockIdx.x * 32], bidx);
    if (tid < 256) {
        const unsigned* f = &flags[(unsigned)tid * 32];
        while (ld_sc_u32(f) < bidx) __builtin_amdgcn_s_sleep(1);
    }
    __syncthreads();
}

// ---------------------------------------------------------------------------
// Persistent scan: 64 steps/launch, 2 barriers/step, 129 barriers/launch.
// 256 blocks x 512 threads, 1 block/CU. LDS tile padded [32][1028].
// ---------------------------------------------------------------------------
__global__ __launch_bounds__(512)
void scan_coop(const float* __restrict__ gates_c,
               const float* __restrict__ WhT,
               const float* __restrict__ prev_ht,
               float* __restrict__ hping,            // [2][32768], sc-only
               float* __restrict__ u_buf,            // sc-only
               float* __restrict__ rh_buf,           // sc-only
               unsigned short* __restrict__ htbf,    // [32][512][1024] bf16
               unsigned* __restrict__ flags,
               int t0, int bidx0)
{
    __shared__ float sh[32*1028];
    __shared__ float red[512];
    const int tid = threadIdx.x;
    const int bid = blockIdx.x;
    unsigned bidx = (unsigned)bidx0;

    if (t0 == 0) {
        long g = (long)bid*512 + tid;
        if (g < 8192) {
            f32x4 v = *(const f32x4*)&prev_ht[g*4];
            st_sc4(&hping[g*4], v);
        }
    }
    flagbar(flags, bidx);     // unconditional: 129 barriers per launch

    for (int tl = 0; tl < 64; ++tl) {
        const int t = t0 + tl;
        const float* hin  = hping + (size_t)(t&1)*32768;
        float*       hout = hping + (size_t)((t+1)&1)*32768;

        // ---- stage h (sc loads, 2 rounds x 8 float4/thread) --------------
#pragma unroll
        for (int r8 = 0; r8 < 2; ++r8) {
            f32x4 v[8];
#pragma unroll
            for (int q = 0; q < 8; ++q) {
                const float* p = &hin[tid*4 + (r8*8+q)*2048];
                asm volatile("global_load_dwordx4 %0, %1, off sc0 sc1"
                             : "=v"(v[q]) : "v"(p));
            }
            asm volatile("s_waitcnt vmcnt(0)" ::: "memory");
            __builtin_amdgcn_sched_barrier(0);
#pragma unroll
            for (int q = 0; q < 8; ++q) {
                int i = tid*4 + (r8*8+q)*2048;
                int n = i >> 10, k = i & 1023;
                *(f32x4*)&sh[n*1028 + k] = v[q];
            }
        }
        __syncthreads();

        // ---------------- phase A: ur = sig(g + h @ Whtg) ----------------
        {
            const int j  = bid*8 + (tid&7);       // 0..2047
            const int n  = (tid>>3) & 31;
            const int kh = tid>>8;                // split-K 2
            const float* wrow = WhT + (size_t)j*1024 + kh*512;
            const float* hrow = sh + n*1028 + kh*512;
            float acc = 0.f;
#pragma unroll 8
            for (int k = 0; k < 512; k += 4) {
                float4 wv = *(const float4*)&wrow[k];
                float4 hv = *(const float4*)&hrow[k];
                acc = fmaf(hv.x, wv.x, acc);
                acc = fmaf(hv.y, wv.y, acc);
                acc = fmaf(hv.z, wv.z, acc);
                acc = fmaf(hv.w, wv.w, acc);
            }
            if (kh) red[tid & 255] = acc;
            __syncthreads();
            if (!kh) {
                acc += red[tid];
                float g = gates_c[(size_t)(n*64 + tl)*3072 + j];
                float s = sigf(g + acc);
                if (j < 1024) st_sc1(&u_buf[n*1024 + j], s);
                else st_sc1(&rh_buf[n*1024 + (j-1024)], s * sh[n*1028 + (j-1024)]);
            }
        }
        flagbar(flags, bidx);

        // ---- stage rh (sc loads) ----------------------------------------
#pragma unroll
        for (int r8 = 0; r8 < 2; ++r8) {
            f32x4 v[8];
#pragma unroll
            for (int q = 0; q < 8; ++q) {
                const float* p = &rh_buf[tid*4 + (r8*8+q)*2048];
                asm volatile("global_load_dwordx4 %0, %1, off sc0 sc1"
                             : "=v"(v[q]) : "v"(p));
            }
            asm volatile("s_waitcnt vmcnt(0)" ::: "memory");
            __builtin_amdgcn_sched_barrier(0);
#pragma unroll
            for (int q = 0; q < 8; ++q) {
                int i = tid*4 + (r8*8+q)*2048;
                int n = i >> 10, k = i & 1023;
                *(f32x4*)&sh[n*1028 + k] = v[q];
            }
        }
        __syncthreads();

        // -------- phase B: hc = tanh(g2 + rh @ Wsm); h' = h + u(hc-h) -----
        {
            const int jb = bid*4 + (tid&3);       // 0..1023
            const int nb = (tid>>2) & 31;
            const int kq = tid>>7;                // split-K 4
            float h0, uu;
            {
                const float* ph = &hin[nb*1024 + jb];
                const float* pu = &u_buf[nb*1024 + jb];
                asm volatile("global_load_dword %0, %1, off sc0 sc1"
                             : "=v"(h0) : "v"(ph));
                asm volatile("global_load_dword %0, %1, off sc0 sc1"
                             : "=v"(uu) : "v"(pu));
            }
            const float* wrow = WhT + (size_t)(2048 + jb)*1024 + kq*256;
            const float* rrow = sh + nb*1028 + kq*256;
            float acc = 0.f;
#pragma unroll 8
            for (int k = 0; k < 256; k += 4) {
                float4 wv = *(const float4*)&wrow[k];
                float4 rv = *(const float4*)&rrow[k];
                acc = fmaf(rv.x, wv.x, acc);
                acc = fmaf(rv.y, wv.y, acc);
                acc = fmaf(rv.z, wv.z, acc);
                acc = fmaf(rv.w, wv.w, acc);
            }
            if (kq) red[(kq-1)*128 + (tid&127)] = acc;
            asm volatile("s_waitcnt vmcnt(0)" ::: "memory");
            __builtin_amdgcn_sched_barrier(0);
            __syncthreads();
            if (!kq) {
                acc += red[tid] + red[128+tid] + red[256+tid];
                float g  = gates_c[(size_t)(nb*64 + tl)*3072 + 2048 + jb];
                float hc = tanhf(g + acc);
                float hn = h0 + uu*(hc - h0);
                st_sc1(&hout[nb*1024 + jb], hn);
                htbf[((size_t)nb*512 + t)*1024 + jb] = f2b(hn);   // plain store
            }
        }
        flagbar(flags, bidx);
    }
}

__global__ __launch_bounds__(256)
void k_lasth(const float* __restrict__ hping, float* __restrict__ dst)
{
    int i = blockIdx.x*256 + threadIdx.x;     // 32768
    dst[i] = hping[i];
}

// ---------------------------------------------------------------------------
extern "C" void kernel_launch(void* const* d_in, const int* in_sizes, int n_in,
                              void* d_out, int out_size, void* d_ws, size_t ws_size,
                              hipStream_t stream)
{
    const float* x       = (const float*)d_in[0];
    const float* prev_ht = (const float*)d_in[1];
    const float* weight  = (const float*)d_in[2];
    const float* bias    = (const float*)d_in[3];
    float* out = (float*)d_out;
    float* ws  = (float*)d_ws;

    // ws layout (float units):
    unsigned short* WT   = (unsigned short*)ws;                // 6,291,456 f
    float* WhT           = ws + 6291456;                       // 3,145,728 f
    float* chunk         = ws + 9437184;                       // 6,291,456 f
    unsigned short* htbf = (unsigned short*)(ws + 15728640);   // 8,388,608 f
    unsigned short* xbf  = (unsigned short*)(ws + 24117248);   // 8,388,608 f
    float* hping         = ws + 32505856;                      // 65,536 f
    float* u_buf         = ws + 32571392;                      // 32,768 f
    float* rh_buf        = ws + 32604160;                      // 32,768 f
    unsigned* flags      = (unsigned*)(ws + 32636928);         // 8,192 u32 (32 KB)
    unsigned short* rxbf = (unsigned short*)(ws + 6291456);    // overlays WhT+chunk
    const size_t needed = (size_t)(32636928 + 8192) * 4;       // 130.6 MB
    if (ws_size < needed) return;

    hipMemsetAsync(flags, 0, 32768, stream);
    k_wt <<<dim3(96,32), 256, 0, stream>>>(weight, WT);
    k_wht<<<dim3(48,16), 256, 0, stream>>>(weight, WhT);
    k_xbf<<<16384, 256, 0, stream>>>(x, xbf);

    for (int seg = 0; seg < 8; ++seg) {
        int t0 = seg * 64;
        int bidx0 = seg * 129;
        gemm_mfma<1,0><<<dim3(24,16), 256, 0, stream>>>(
            xbf, nullptr, WT, chunk, 3072, bias, nullptr, nullptr, nullptr,
            1024, t0);
        const float* gc = chunk;
        void* args[] = { (void*)&gc, (void*)&WhT, (void*)&prev_ht,
                         (void*)&hping, (void*)&u_buf, (void*)&rh_buf,
                         (void*)&htbf, (void*)&flags, (void*)&t0, (void*)&bidx0 };
        hipLaunchCooperativeKernel((void*)scan_coop, dim3(256), dim3(512),
                                   args, 0, stream);
    }

    // depth urd: [x|ht] @ W[:,3072:5120] -> sig -> ud (d_out), rx (bf16)
    gemm_mfma<2,1><<<dim3(16,128), 256, 0, stream>>>(
        xbf, htbf, WT + (size_t)3072*2048, nullptr, 0, bias + 3072,
        x, out, rxbf, 2048, 0);
    // depth hc: [rx|ht] @ W[:,5120:6144] -> tanh -> final out
    gemm_mfma<2,2><<<dim3(8,128), 256, 0, stream>>>(
        rxbf, htbf, WT + (size_t)5120*2048, out, 1024, bias + 5120,
        x, out, nullptr, 2048, 0);

    k_lasth<<<128, 256, 0, stream>>>(hping, out + (size_t)16384*1024);
}